// Round 1
// baseline (369.924 us; speedup 1.0000x reference)
//
#include <hip/hip_runtime.h>
#include <hip/hip_bf16.h>
#include <math.h>

#define NPTS 100000
#define KOFF 27

typedef __attribute__((ext_vector_type(8))) __bf16 bf16x8;
typedef __attribute__((ext_vector_type(4))) float f32x4;

__device__ __forceinline__ unsigned short f2bf(float f) {
    unsigned int u = __float_as_uint(f);
    u += 0x7fffu + ((u >> 16) & 1u);   // RNE; NaN not expected in this workload
    return (unsigned short)(u >> 16);
}

__device__ __forceinline__ float gelu_erf(float v) {
    return 0.5f * v * (1.0f + erff(v * 0.70710678118654752f));
}

// ---------------------------------------------------------------------------
// Kernel 0: repack W1/W2 (fp32 -> bf16) into per-lane MFMA B-fragment order,
// and sniff mask dtype (bool bytes vs int32) into *flagp.
//   W1p[((k*8+ct)*64+lane)*8 + j] = bf16(W1[k][ (lane>>4)*8+j ][ ct*16+(lane&15) ])
//   W2p[(((k*4+kc)*2+ct)*64+lane)*8 + j]
//       = bf16(W2[k][ kc*32+(lane>>4)*8+j ][ ct*16+(lane&15) ])
// ---------------------------------------------------------------------------
__global__ __launch_bounds__(256)
void repack_kernel(const float* __restrict__ W1, const float* __restrict__ W2,
                   const void* __restrict__ maskp,
                   unsigned short* __restrict__ W1p,
                   unsigned short* __restrict__ W2p,
                   int* __restrict__ flagp) {
    int o = blockIdx.x * 256 + threadIdx.x;
    if (o == 0) {
        const unsigned int* mw = (const unsigned int*)maskp;
        int f = 0;
        for (int i = 0; i < 64; ++i) f |= (mw[i] > 1u) ? 1 : 0;
        *flagp = f;   // 1 => byte/bool mask, 0 => int32 mask
    }
    if (o < KOFF * 32 * 128) {
        int j = o & 7, lane = (o >> 3) & 63;
        int quad = lane >> 4, nn = lane & 15;
        // W1: [27][32][128]
        int ct1 = (o >> 9) & 7, k1 = o >> 12;
        int kk1 = quad * 8 + j;
        W1p[o] = f2bf(W1[(k1 * 32 + kk1) * 128 + (ct1 * 16 + nn)]);
        // W2: [27][128][32]
        int ct2 = (o >> 9) & 1, kc2 = (o >> 10) & 3, k2 = o >> 12;
        int kk2 = kc2 * 32 + quad * 8 + j;
        W2p[o] = f2bf(W2[(k2 * 128 + kk2) * 32 + (ct2 * 16 + nn)]);
    }
}

// ---------------------------------------------------------------------------
// Kernel 1: out0 = bf16( gelu( LN( x @ W_conv ) ) )   [N,32]
// 8 rows/block, thread t -> (row t>>5, col t&31); fp32 VALU.
// ---------------------------------------------------------------------------
__global__ __launch_bounds__(256)
void conv1_ln_gelu(const float* __restrict__ x, const float* __restrict__ Wc,
                   const float* __restrict__ g0, const float* __restrict__ b0,
                   unsigned short* __restrict__ out0) {
    __shared__ float xs[256];    // 8 rows x 32
    __shared__ float wc[1024];   // 32 x 32
    int t = threadIdx.x;
    int nb = blockIdx.x * 8;     // N % 8 == 0 -> always full
    xs[t] = x[nb * 32 + t];
    for (int i = t; i < 1024; i += 256) wc[i] = Wc[i];
    __syncthreads();
    int r = t >> 5, d = t & 31;
    const float* xr = &xs[r * 32];
    float v = 0.f;
#pragma unroll
    for (int c = 0; c < 32; ++c) v = fmaf(xr[c], wc[c * 32 + d], v);
    float s = v, s2 = v * v;
#pragma unroll
    for (int m = 16; m >= 1; m >>= 1) {
        s  += __shfl_xor(s,  m, 32);
        s2 += __shfl_xor(s2, m, 32);
    }
    float mu  = s * (1.f / 32.f);
    float var = s2 * (1.f / 32.f) - mu * mu;
    float y = (v - mu) * rsqrtf(var + 1e-6f) * g0[d] + b0[d];
    out0[nb * 32 + t] = f2bf(gelu_erf(y));
}

// ---------------------------------------------------------------------------
// Shared helper: stage masked gather indices for 64 rows into LDS (-1 = skip)
// ---------------------------------------------------------------------------
__device__ __forceinline__ void stage_gidx(int* s_gidx, const int* nidx,
                                           const void* maskp, int mflag,
                                           int nb, int t) {
    int cnt = (NPTS - nb < 64 ? NPTS - nb : 64) * KOFF;
    for (int i = t; i < 64 * KOFF; i += 256) {
        int g = -1;
        if (i < cnt) {
            int gi = nidx[nb * KOFF + i];
            int m = mflag ? (int)((const unsigned char*)maskp)[nb * KOFF + i]
                          : ((const int*)maskp)[nb * KOFF + i];
            g = m ? gi : -1;
        }
        s_gidx[i] = g;
    }
}

// ---------------------------------------------------------------------------
// Kernel 2: out1 = bf16( gelu( LN( sparse_conv(out0, W1) ) ) )   [N,128]
// 64 rows/block, 4 waves; wave w owns col-tiles {2w, 2w+1}, all 4 row-tiles.
// MFMA 16x16x32 bf16, fp32 accum.
// ---------------------------------------------------------------------------
__global__ __launch_bounds__(256)
void conv_k1(const int* __restrict__ nidx, const void* __restrict__ maskp,
             const int* __restrict__ flagp,
             const unsigned short* __restrict__ out0,
             const unsigned short* __restrict__ W1p,
             const float* __restrict__ g1, const float* __restrict__ b1,
             unsigned short* __restrict__ out1) {
    __shared__ int   s_gidx[64 * KOFF];
    __shared__ float tile[64 * 132];      // +4 pad breaks store conflicts
    __shared__ float s_mu[64], s_rs[64];
    __shared__ float s_g[128], s_b[128];

    int t = threadIdx.x;
    int nb = blockIdx.x * 64;
    int mflag = *flagp;
    if (t < 128) { s_g[t] = g1[t]; s_b[t] = b1[t]; }
    stage_gidx(s_gidx, nidx, maskp, mflag, nb, t);
    __syncthreads();

    int lane = t & 63, w = t >> 6;
    int mrow = lane & 15, quad = lane >> 4;
    f32x4 acc[4][2] = {};

    for (int k = 0; k < KOFF; ++k) {
        bf16x8 bfr[2];
#pragma unroll
        for (int j = 0; j < 2; ++j) {
            int ct = w * 2 + j;
            bfr[j] = *reinterpret_cast<const bf16x8*>(W1p + (((k * 8 + ct) * 64 + lane) << 3));
        }
#pragma unroll
        for (int rt = 0; rt < 4; ++rt) {
            int g = s_gidx[(rt * 16 + mrow) * KOFF + k];
            bf16x8 afr = {};
            if (g >= 0)
                afr = *reinterpret_cast<const bf16x8*>(out0 + g * 32 + quad * 8);
#pragma unroll
            for (int j = 0; j < 2; ++j)
                acc[rt][j] = __builtin_amdgcn_mfma_f32_16x16x32_bf16(afr, bfr[j], acc[rt][j], 0, 0, 0);
        }
    }

    // scatter accumulators to LDS tile (C/D layout: col=lane&15, row=quad*4+reg)
#pragma unroll
    for (int rt = 0; rt < 4; ++rt)
#pragma unroll
        for (int j = 0; j < 2; ++j) {
            int col = w * 32 + j * 16 + mrow;
#pragma unroll
            for (int reg = 0; reg < 4; ++reg)
                tile[(rt * 16 + quad * 4 + reg) * 132 + col] = acc[rt][j][reg];
        }
    __syncthreads();

    // LN over 128 cols: 4 threads per row
    int r = t >> 2, q = t & 3;
    float s = 0.f, s2 = 0.f;
#pragma unroll
    for (int i = 0; i < 32; ++i) {
        float v = tile[r * 132 + q * 32 + i];
        s += v; s2 += v * v;
    }
    s += __shfl_xor(s, 1, 4); s2 += __shfl_xor(s2, 1, 4);
    s += __shfl_xor(s, 2, 4); s2 += __shfl_xor(s2, 2, 4);
    if (q == 0) {
        float mu  = s * (1.f / 128.f);
        float var = s2 * (1.f / 128.f) - mu * mu;
        s_mu[r] = mu; s_rs[r] = rsqrtf(var + 1e-6f);
    }
    __syncthreads();

#pragma unroll
    for (int i = 0; i < 32; ++i) {
        int e = i * 256 + t;
        int rr = e >> 7, c = e & 127;
        int n = nb + rr;
        if (n < NPTS) {
            float v = tile[rr * 132 + c];
            float y = (v - s_mu[rr]) * s_rs[rr] * s_g[c] + s_b[c];
            out1[n * 128 + c] = f2bf(gelu_erf(y));
        }
    }
}

// ---------------------------------------------------------------------------
// Kernel 3: out = gelu( LN( sparse_conv(out1, W2) ) + x )   [N,32] fp32
// 64 rows/block, 4 waves in 2x2 split: wr=w>>1 (32 rows), wc=w&1 (1 col-tile).
// K per offset = 128 -> 4 MFMA chunks.
// ---------------------------------------------------------------------------
__global__ __launch_bounds__(256)
void conv_k2(const int* __restrict__ nidx, const void* __restrict__ maskp,
             const int* __restrict__ flagp,
             const unsigned short* __restrict__ out1,
             const unsigned short* __restrict__ W2p,
             const float* __restrict__ g2, const float* __restrict__ b2,
             const float* __restrict__ x, float* __restrict__ outp) {
    __shared__ int   s_gidx[64 * KOFF];
    __shared__ float tile[64 * 33];
    __shared__ float s_mu[64], s_rs[64];
    __shared__ float s_g[32], s_b[32];

    int t = threadIdx.x;
    int nb = blockIdx.x * 64;
    int mflag = *flagp;
    if (t < 32) { s_g[t] = g2[t]; s_b[t] = b2[t]; }
    stage_gidx(s_gidx, nidx, maskp, mflag, nb, t);
    __syncthreads();

    int lane = t & 63, w = t >> 6;
    int wr = w >> 1, wc = w & 1;
    int mrow = lane & 15, quad = lane >> 4;
    f32x4 acc[2] = {};

    for (int k = 0; k < KOFF; ++k) {
        int ga = s_gidx[(wr * 32 + mrow) * KOFF + k];
        int gb = s_gidx[(wr * 32 + 16 + mrow) * KOFF + k];
#pragma unroll
        for (int kc = 0; kc < 4; ++kc) {
            bf16x8 bfr = *reinterpret_cast<const bf16x8*>(
                W2p + ((((k * 4 + kc) * 2 + wc) * 64 + lane) << 3));
            bf16x8 a0 = {}, a1 = {};
            if (ga >= 0)
                a0 = *reinterpret_cast<const bf16x8*>(out1 + ga * 128 + kc * 32 + quad * 8);
            if (gb >= 0)
                a1 = *reinterpret_cast<const bf16x8*>(out1 + gb * 128 + kc * 32 + quad * 8);
            acc[0] = __builtin_amdgcn_mfma_f32_16x16x32_bf16(a0, bfr, acc[0], 0, 0, 0);
            acc[1] = __builtin_amdgcn_mfma_f32_16x16x32_bf16(a1, bfr, acc[1], 0, 0, 0);
        }
    }

#pragma unroll
    for (int rt = 0; rt < 2; ++rt) {
        int col = wc * 16 + mrow;
#pragma unroll
        for (int reg = 0; reg < 4; ++reg)
            tile[(wr * 32 + rt * 16 + quad * 4 + reg) * 33 + col] = acc[rt][reg];
    }
    __syncthreads();

    int r = t >> 2, q = t & 3;
    float s = 0.f, s2 = 0.f;
#pragma unroll
    for (int i = 0; i < 8; ++i) {
        float v = tile[r * 33 + q * 8 + i];
        s += v; s2 += v * v;
    }
    s += __shfl_xor(s, 1, 4); s2 += __shfl_xor(s2, 1, 4);
    s += __shfl_xor(s, 2, 4); s2 += __shfl_xor(s2, 2, 4);
    if (q == 0) {
        float mu  = s * (1.f / 32.f);
        float var = s2 * (1.f / 32.f) - mu * mu;
        s_mu[r] = mu; s_rs[r] = rsqrtf(var + 1e-6f);
    }
    __syncthreads();

#pragma unroll
    for (int i = 0; i < 8; ++i) {
        int e = i * 256 + t;
        int rr = e >> 5, c = e & 31;
        int n = nb + rr;
        if (n < NPTS) {
            float v = tile[rr * 33 + c];
            float y = (v - s_mu[rr]) * s_rs[rr] * s_g[c] + s_b[c];
            outp[n * 32 + c] = gelu_erf(y + x[n * 32 + c]);
        }
    }
}

// ---------------------------------------------------------------------------
extern "C" void kernel_launch(void* const* d_in, const int* in_sizes, int n_in,
                              void* d_out, int out_size, void* d_ws, size_t ws_size,
                              hipStream_t stream) {
    const float* x    = (const float*)d_in[0];
    const int*   nidx = (const int*)d_in[1];
    const void*  maskp = d_in[2];
    const float* Wc = (const float*)d_in[3];
    const float* g0 = (const float*)d_in[4];
    const float* b0 = (const float*)d_in[5];
    const float* W1 = (const float*)d_in[6];
    const float* g1 = (const float*)d_in[7];
    const float* b1 = (const float*)d_in[8];
    const float* W2 = (const float*)d_in[9];
    const float* g2 = (const float*)d_in[10];
    const float* b2 = (const float*)d_in[11];

    char* ws = (char*)d_ws;
    unsigned short* out0 = (unsigned short*)ws;                    // 100000*32*2  = 6.4 MB
    unsigned short* out1 = (unsigned short*)(ws + 6400000);        // 100000*128*2 = 25.6 MB
    unsigned short* W1p  = (unsigned short*)(ws + 32000000);       // 110592*2
    unsigned short* W2p  = W1p + KOFF * 32 * 128;                  // 110592*2
    int* flagp = (int*)(W2p + KOFF * 128 * 32);

    repack_kernel<<<432, 256, 0, stream>>>(W1, W2, maskp, W1p, W2p, flagp);
    conv1_ln_gelu<<<NPTS / 8, 256, 0, stream>>>(x, Wc, g0, b0, out0);
    conv_k1<<<(NPTS + 63) / 64, 256, 0, stream>>>(nidx, maskp, flagp, out0, W1p, g1, b1, out1);
    conv_k2<<<(NPTS + 63) / 64, 256, 0, stream>>>(nidx, maskp, flagp, out1, W2p, g2, b2, x, (float*)d_out);
}

// Round 2
// 289.684 us; speedup vs baseline: 1.2770x; 1.2770x over previous
//
#include <hip/hip_runtime.h>
#include <hip/hip_bf16.h>
#include <math.h>

#define NPTS 100000
#define KOFF 27

typedef __attribute__((ext_vector_type(8))) __bf16 bf16x8;
typedef __attribute__((ext_vector_type(4))) float f32x4;

__device__ __forceinline__ unsigned short f2bf(float f) {
    unsigned int u = __float_as_uint(f);
    u += 0x7fffu + ((u >> 16) & 1u);   // RNE
    return (unsigned short)(u >> 16);
}

__device__ __forceinline__ float gelu_erf(float v) {
    return 0.5f * v * (1.0f + erff(v * 0.70710678118654752f));
}

// ---------------------------------------------------------------------------
// Kernel 0: repack W1/W2 (fp32 -> bf16) into per-lane MFMA B-fragment order,
// and sniff mask dtype (bool bytes vs int32) into *flagp.
//   W1p[((k*8+ct)*64+lane)*8 + j] = bf16(W1[k][ (lane>>4)*8+j ][ ct*16+(lane&15) ])
//   W2p[(((k*4+kc)*2+ct)*64+lane)*8 + j]
//       = bf16(W2[k][ kc*32+(lane>>4)*8+j ][ ct*16+(lane&15) ])
// ---------------------------------------------------------------------------
__global__ __launch_bounds__(256)
void repack_kernel(const float* __restrict__ W1, const float* __restrict__ W2,
                   const void* __restrict__ maskp,
                   unsigned short* __restrict__ W1p,
                   unsigned short* __restrict__ W2p,
                   int* __restrict__ flagp) {
    int o = blockIdx.x * 256 + threadIdx.x;
    if (o == 0) {
        const unsigned int* mw = (const unsigned int*)maskp;
        int f = 0;
        for (int i = 0; i < 64; ++i) f |= (mw[i] > 1u) ? 1 : 0;
        *flagp = f;   // 1 => byte/bool mask, 0 => int32 mask
    }
    if (o < KOFF * 32 * 128) {
        int j = o & 7, lane = (o >> 3) & 63;
        int quad = lane >> 4, nn = lane & 15;
        int ct1 = (o >> 9) & 7, k1 = o >> 12;
        int kk1 = quad * 8 + j;
        W1p[o] = f2bf(W1[(k1 * 32 + kk1) * 128 + (ct1 * 16 + nn)]);
        int ct2 = (o >> 9) & 1, kc2 = (o >> 10) & 3, k2 = o >> 12;
        int kk2 = kc2 * 32 + quad * 8 + j;
        W2p[o] = f2bf(W2[(k2 * 128 + kk2) * 32 + (ct2 * 16 + nn)]);
    }
}

// ---------------------------------------------------------------------------
// Kernel 1: out0 = bf16( gelu( LN( x @ W_conv ) ) )   [N,32]
// ---------------------------------------------------------------------------
__global__ __launch_bounds__(256)
void conv1_ln_gelu(const float* __restrict__ x, const float* __restrict__ Wc,
                   const float* __restrict__ g0, const float* __restrict__ b0,
                   unsigned short* __restrict__ out0) {
    __shared__ float xs[256];
    __shared__ float wc[1024];
    int t = threadIdx.x;
    int nb = blockIdx.x * 8;
    xs[t] = x[nb * 32 + t];
    for (int i = t; i < 1024; i += 256) wc[i] = Wc[i];
    __syncthreads();
    int r = t >> 5, d = t & 31;
    const float* xr = &xs[r * 32];
    float v = 0.f;
#pragma unroll
    for (int c = 0; c < 32; ++c) v = fmaf(xr[c], wc[c * 32 + d], v);
    float s = v, s2 = v * v;
#pragma unroll
    for (int m = 16; m >= 1; m >>= 1) {
        s  += __shfl_xor(s,  m, 32);
        s2 += __shfl_xor(s2, m, 32);
    }
    float mu  = s * (1.f / 32.f);
    float var = s2 * (1.f / 32.f) - mu * mu;
    float y = (v - mu) * rsqrtf(var + 1e-6f) * g0[d] + b0[d];
    out0[nb * 32 + t] = f2bf(gelu_erf(y));
}

// ---------------------------------------------------------------------------
// Stage masked gather indices for 64 rows into LDS (-1 = skip)
// ---------------------------------------------------------------------------
__device__ __forceinline__ void stage_gidx(int* s_gidx, const int* nidx,
                                           const void* maskp, int mflag,
                                           int nb, int t) {
    int cnt = (NPTS - nb < 64 ? NPTS - nb : 64) * KOFF;
    for (int i = t; i < 64 * KOFF; i += 256) {
        int g = -1;
        if (i < cnt) {
            int gi = nidx[nb * KOFF + i];
            int m = mflag ? (int)((const unsigned char*)maskp)[nb * KOFF + i]
                          : ((const int*)maskp)[nb * KOFF + i];
            g = m ? gi : -1;
        }
        s_gidx[i] = g;
    }
}

// ---------------------------------------------------------------------------
// Kernel 2: out1 = bf16( gelu( LN( sparse_conv(out0, W1) ) ) )   [N,128]
// 64 rows/block, 4 waves; wave w owns row-tile w EXCLUSIVELY, computes all
// 8 col-tiles. One A-gather per lane per k; prefetch depth 1 (idx depth 2).
// LN fully in-register via width-16 shfl (row's 128 cols live on one quad).
// ---------------------------------------------------------------------------
__global__ __launch_bounds__(256, 4)
void conv_k1(const int* __restrict__ nidx, const void* __restrict__ maskp,
             const int* __restrict__ flagp,
             const unsigned short* __restrict__ out0,
             const unsigned short* __restrict__ W1p,
             const float* __restrict__ g1, const float* __restrict__ b1,
             unsigned short* __restrict__ out1) {
    __shared__ int   s_gidx[64 * KOFF];
    __shared__ float s_g[128], s_b[128];

    int t = threadIdx.x;
    int nb = blockIdx.x * 64;
    int mflag = *flagp;
    if (t < 128) { s_g[t] = g1[t]; s_b[t] = b1[t]; }
    stage_gidx(s_gidx, nidx, maskp, mflag, nb, t);
    __syncthreads();

    int lane = t & 63, w = t >> 6;
    int mrow = lane & 15, quad = lane >> 4;
    const int* gp = &s_gidx[(w * 16 + mrow) * KOFF];

    f32x4 acc[8] = {};
    int gnxt = gp[1];
    {
        int g0i = gp[0];
        // fallthrough into loop below via a_nxt
        bf16x8 tmp = {};
        if (g0i >= 0) tmp = *reinterpret_cast<const bf16x8*>(out0 + g0i * 32 + quad * 8);
        // store in a_nxt
        bf16x8 a_nxt = tmp;
        for (int k = 0; k < KOFF; ++k) {
            bf16x8 a_cur = a_nxt;
            int gtmp = gnxt;
            gnxt = gp[k + 2 < KOFF ? k + 2 : KOFF - 1];
            a_nxt = bf16x8{};
            if (gtmp >= 0)
                a_nxt = *reinterpret_cast<const bf16x8*>(out0 + gtmp * 32 + quad * 8);
            const unsigned short* wb = W1p + (((k * 8) * 64 + lane) << 3);
#pragma unroll
            for (int ct = 0; ct < 8; ++ct) {
                bf16x8 bfr = *reinterpret_cast<const bf16x8*>(wb + ((ct * 64) << 3));
                acc[ct] = __builtin_amdgcn_mfma_f32_16x16x32_bf16(a_cur, bfr, acc[ct], 0, 0, 0);
            }
        }
    }

    // Epilogue: LN(128) + GELU, all in-register.
    // acc[ct][r] = C[row = quad*4+r][col = ct*16+mrow], global row nb+w*16+quad*4+r
    int n_base = nb + w * 16 + quad * 4;
#pragma unroll
    for (int r = 0; r < 4; ++r) {
        float s = 0.f, s2 = 0.f;
#pragma unroll
        for (int ct = 0; ct < 8; ++ct) { float v = acc[ct][r]; s += v; s2 += v * v; }
#pragma unroll
        for (int m = 1; m <= 8; m <<= 1) {
            s  += __shfl_xor(s,  m, 16);
            s2 += __shfl_xor(s2, m, 16);
        }
        float mu = s * (1.f / 128.f);
        float rs = rsqrtf(s2 * (1.f / 128.f) - mu * mu + 1e-6f);
        int n = n_base + r;
        if (n < NPTS) {
#pragma unroll
            for (int ct = 0; ct < 8; ++ct) {
                int c = ct * 16 + mrow;
                float y = (acc[ct][r] - mu) * rs * s_g[c] + s_b[c];
                out1[n * 128 + c] = f2bf(gelu_erf(y));
            }
        }
    }
}

// ---------------------------------------------------------------------------
// Kernel 3: out = gelu( LN( sparse_conv(out1, W2) ) + x )   [N,32] fp32
// 64 rows/block, wave w owns row-tile w, computes both col-tiles.
// Per k: gather 4 x 16B chunks of lane's row (contiguous 64B), 8 B-frags, 8 MFMA.
// ---------------------------------------------------------------------------
__global__ __launch_bounds__(256, 4)
void conv_k2(const int* __restrict__ nidx, const void* __restrict__ maskp,
             const int* __restrict__ flagp,
             const unsigned short* __restrict__ out1,
             const unsigned short* __restrict__ W2p,
             const float* __restrict__ g2, const float* __restrict__ b2,
             const float* __restrict__ x, float* __restrict__ outp) {
    __shared__ int   s_gidx[64 * KOFF];
    __shared__ float s_g[32], s_b[32];

    int t = threadIdx.x;
    int nb = blockIdx.x * 64;
    int mflag = *flagp;
    if (t < 32) { s_g[t] = g2[t]; s_b[t] = b2[t]; }
    stage_gidx(s_gidx, nidx, maskp, mflag, nb, t);
    __syncthreads();

    int lane = t & 63, w = t >> 6;
    int mrow = lane & 15, quad = lane >> 4;
    const int* gp = &s_gidx[(w * 16 + mrow) * KOFF];

    f32x4 acc[2] = {};
    int gnxt = gp[1];
    bf16x8 a_nxt[4] = {};
    {
        int g0i = gp[0];
        if (g0i >= 0) {
#pragma unroll
            for (int kc = 0; kc < 4; ++kc)
                a_nxt[kc] = *reinterpret_cast<const bf16x8*>(out1 + g0i * 128 + kc * 32 + quad * 8);
        }
    }
    for (int k = 0; k < KOFF; ++k) {
        bf16x8 a_cur[4];
#pragma unroll
        for (int kc = 0; kc < 4; ++kc) a_cur[kc] = a_nxt[kc];
        int gtmp = gnxt;
        gnxt = gp[k + 2 < KOFF ? k + 2 : KOFF - 1];
#pragma unroll
        for (int kc = 0; kc < 4; ++kc) a_nxt[kc] = bf16x8{};
        if (gtmp >= 0) {
#pragma unroll
            for (int kc = 0; kc < 4; ++kc)
                a_nxt[kc] = *reinterpret_cast<const bf16x8*>(out1 + gtmp * 128 + kc * 32 + quad * 8);
        }
        const unsigned short* wb = W2p + (((k * 8) * 64 + lane) << 3);
#pragma unroll
        for (int kc = 0; kc < 4; ++kc) {
            bf16x8 b0 = *reinterpret_cast<const bf16x8*>(wb + (((kc * 2 + 0) * 64) << 3));
            bf16x8 b1 = *reinterpret_cast<const bf16x8*>(wb + (((kc * 2 + 1) * 64) << 3));
            acc[0] = __builtin_amdgcn_mfma_f32_16x16x32_bf16(a_cur[kc], b0, acc[0], 0, 0, 0);
            acc[1] = __builtin_amdgcn_mfma_f32_16x16x32_bf16(a_cur[kc], b1, acc[1], 0, 0, 0);
        }
    }

    // Epilogue: LN(32) + residual + GELU, in-register.
    // acc[ct][r] = C[row=quad*4+r][col=ct*16+mrow]
    int n_base = nb + w * 16 + quad * 4;
#pragma unroll
    for (int r = 0; r < 4; ++r) {
        float v0 = acc[0][r], v1 = acc[1][r];
        float s = v0 + v1, s2 = v0 * v0 + v1 * v1;
#pragma unroll
        for (int m = 1; m <= 8; m <<= 1) {
            s  += __shfl_xor(s,  m, 16);
            s2 += __shfl_xor(s2, m, 16);
        }
        float mu = s * (1.f / 32.f);
        float rs = rsqrtf(s2 * (1.f / 32.f) - mu * mu + 1e-6f);
        int n = n_base + r;
        if (n < NPTS) {
            int c0 = mrow, c1 = mrow + 16;
            float y0 = (v0 - mu) * rs * s_g[c0] + s_b[c0] + x[n * 32 + c0];
            float y1 = (v1 - mu) * rs * s_g[c1] + s_b[c1] + x[n * 32 + c1];
            outp[n * 32 + c0] = gelu_erf(y0);
            outp[n * 32 + c1] = gelu_erf(y1);
        }
    }
}

// ---------------------------------------------------------------------------
extern "C" void kernel_launch(void* const* d_in, const int* in_sizes, int n_in,
                              void* d_out, int out_size, void* d_ws, size_t ws_size,
                              hipStream_t stream) {
    const float* x    = (const float*)d_in[0];
    const int*   nidx = (const int*)d_in[1];
    const void*  maskp = d_in[2];
    const float* Wc = (const float*)d_in[3];
    const float* g0 = (const float*)d_in[4];
    const float* b0 = (const float*)d_in[5];
    const float* W1 = (const float*)d_in[6];
    const float* g1 = (const float*)d_in[7];
    const float* b1 = (const float*)d_in[8];
    const float* W2 = (const float*)d_in[9];
    const float* g2 = (const float*)d_in[10];
    const float* b2 = (const float*)d_in[11];

    char* ws = (char*)d_ws;
    unsigned short* out0 = (unsigned short*)ws;                    // 6.4 MB
    unsigned short* out1 = (unsigned short*)(ws + 6400000);        // 25.6 MB
    unsigned short* W1p  = (unsigned short*)(ws + 32000000);       // 221 KB
    unsigned short* W2p  = W1p + KOFF * 32 * 128;                  // 221 KB
    int* flagp = (int*)(W2p + KOFF * 128 * 32);

    repack_kernel<<<432, 256, 0, stream>>>(W1, W2, maskp, W1p, W2p, flagp);
    conv1_ln_gelu<<<NPTS / 8, 256, 0, stream>>>(x, Wc, g0, b0, out0);
    conv_k1<<<(NPTS + 63) / 64, 256, 0, stream>>>(nidx, maskp, flagp, out0, W1p, g1, b1, out1);
    conv_k2<<<(NPTS + 63) / 64, 256, 0, stream>>>(nidx, maskp, flagp, out1, W2p, g2, b2, x, (float*)d_out);
}